// Round 1
// baseline (1869.929 us; speedup 1.0000x reference)
//
#include <hip/hip_runtime.h>
#include <hip/hip_bf16.h>

#define SEQ  2048
#define DMODEL 1024
#define NHEADS 16
#define HD   64
#define EPS_LA 1e-5f

// ---------------------------------------------------------------------------
// Tiled fp32 GEMM: C = A(MxK) * B(KxN), row-major, optional relu on columns
// < relu_limit. BM=BN=128, BK=8, 256 threads, 8x8 per thread.
// M,N,K must be multiples of 128/128/8 (true here).
// ---------------------------------------------------------------------------
__global__ __launch_bounds__(256) void gemm_relu_f32(
    const float* __restrict__ A, const float* __restrict__ B,
    float* __restrict__ C, int M, int N, int K, int relu_limit) {
  __shared__ float As[8][128];
  __shared__ float Bs[8][128];
  const int tid  = threadIdx.x;
  const int brow = blockIdx.y * 128;
  const int bcol = blockIdx.x * 128;
  const int tr = (tid >> 4) << 3;   // 0..120 step 8
  const int tc = (tid & 15) << 3;

  float acc[8][8];
  #pragma unroll
  for (int i = 0; i < 8; ++i)
    #pragma unroll
    for (int j = 0; j < 8; ++j) acc[i][j] = 0.f;

  // A tile load: 128 rows x 8 k  -> thread (ar = tid>>1, ak4 = (tid&1)*4)
  const int ar  = tid >> 1;
  const int ak4 = (tid & 1) * 4;
  // B tile load: 8 k x 128 cols  -> thread (bk = tid>>5, bc4 = (tid&31)*4)
  const int bk  = tid >> 5;
  const int bc4 = (tid & 31) * 4;

  const float* Aptr = A + (size_t)(brow + ar) * K + ak4;
  const float* Bptr = B + (size_t)bk * N + bcol + bc4;

  for (int k0 = 0; k0 < K; k0 += 8) {
    float4 av = *(const float4*)(Aptr + k0);
    float4 bv = *(const float4*)(Bptr + (size_t)k0 * N);
    As[ak4 + 0][ar] = av.x;
    As[ak4 + 1][ar] = av.y;
    As[ak4 + 2][ar] = av.z;
    As[ak4 + 3][ar] = av.w;
    *(float4*)&Bs[bk][bc4] = bv;
    __syncthreads();
    #pragma unroll
    for (int kk = 0; kk < 8; ++kk) {
      float ra[8], rb[8];
      #pragma unroll
      for (int i = 0; i < 8; ++i) ra[i] = As[kk][tr + i];
      #pragma unroll
      for (int j = 0; j < 8; ++j) rb[j] = Bs[kk][tc + j];
      #pragma unroll
      for (int i = 0; i < 8; ++i)
        #pragma unroll
        for (int j = 0; j < 8; ++j)
          acc[i][j] = fmaf(ra[i], rb[j], acc[i][j]);
    }
    __syncthreads();
  }

  #pragma unroll
  for (int i = 0; i < 8; ++i) {
    const int row = brow + tr + i;
    float* crow = C + (size_t)row * N + bcol;
    #pragma unroll
    for (int j = 0; j < 8; ++j) {
      float val = acc[i][j];
      if (bcol + tc + j < relu_limit) val = fmaxf(val, 0.f);
      crow[tc + j] = val;
    }
  }
}

// ---------------------------------------------------------------------------
// Sequential linear-attention scan. One block per (b,h). 256 threads.
// Thread t: e = t>>2 (output/v index), dg = t&3 (d-group). Thread owns
// kv[d][e] for d = dg*16 .. dg*16+15 in registers.
//   kv[d][e] += k[d]*v[e];  num[e] = sum_d q[d]*kv[d][e]
//   ksum[d] += k[d];        den    = sum_d q[d]*ksum[d] + eps
//   y[e] = num[e]/den
// qkv layout: (b, n, 3*DMODEL): q at [0,1024), k at [1024,2048), v at [2048,3072)
// ---------------------------------------------------------------------------
__global__ __launch_bounds__(256) void linattn_scan(
    const float* __restrict__ qkv, float* __restrict__ y) {
  const int b   = blockIdx.x >> 4;
  const int h   = blockIdx.x & 15;
  const int tid = threadIdx.x;
  const int dg  = tid & 3;
  const int e   = tid >> 2;

  __shared__ float sh[192];      // [0,64)=q  [64,128)=k  [128,192)=v
  __shared__ float den_sh;

  float kvloc[16];
  #pragma unroll
  for (int i = 0; i < 16; ++i) kvloc[i] = 0.f;
  float ksum = 0.f;

  const size_t base = ((size_t)b * SEQ) * (3 * DMODEL) + (size_t)h * HD;
  const int seg = tid >> 6;      // 0=q 1=k 2=v (tid<192)
  const int off = tid & 63;
  const float* lptr = qkv + base + (size_t)seg * DMODEL + off;

  float nxt = (tid < 192) ? lptr[0] : 0.f;

  for (int t = 0; t < SEQ; ++t) {
    if (tid < 192) sh[tid] = nxt;
    __syncthreads();
    if (tid < 192 && t + 1 < SEQ)
      nxt = lptr[(size_t)(t + 1) * (3 * DMODEL)];

    const float vv = sh[128 + e];
    float num = 0.f;
    #pragma unroll
    for (int i = 0; i < 16; ++i) {
      const float qd = sh[dg * 16 + i];
      const float kd = sh[64 + dg * 16 + i];
      kvloc[i] = fmaf(kd, vv, kvloc[i]);
      num = fmaf(qd, kvloc[i], num);
    }
    num += __shfl_xor(num, 1);
    num += __shfl_xor(num, 2);

    if (tid < 64) {
      ksum += sh[64 + tid];
      float denp = sh[tid] * ksum;
      #pragma unroll
      for (int o = 32; o > 0; o >>= 1) denp += __shfl_xor(denp, o);
      if (tid == 0) den_sh = denp;
    }
    __syncthreads();

    if (dg == 0) {
      y[((size_t)(b * SEQ + t)) * DMODEL + (size_t)h * HD + e] =
          num / (den_sh + EPS_LA);
    }
  }
}

// ---------------------------------------------------------------------------
extern "C" void kernel_launch(void* const* d_in, const int* in_sizes, int n_in,
                              void* d_out, int out_size, void* d_ws,
                              size_t ws_size, hipStream_t stream) {
  (void)in_sizes; (void)n_in; (void)out_size; (void)ws_size;
  const float* x    = (const float*)d_in[0];
  const float* wqkv = (const float*)d_in[1];
  const float* wo   = (const float*)d_in[2];
  float* out = (float*)d_out;

  const int M  = 2 * SEQ;   // 4096
  const int K  = DMODEL;    // 1024
  const int N1 = 3 * DMODEL;// 3072
  const int N2 = DMODEL;    // 1024

  float* qkv = (float*)d_ws;                       // 48 MB
  float* y   = qkv + (size_t)M * N1;               // 16 MB

  dim3 blk(256);
  dim3 g1(N1 / 128, M / 128);
  gemm_relu_f32<<<g1, blk, 0, stream>>>(x, wqkv, qkv, M, N1, K, 2 * DMODEL);

  linattn_scan<<<dim3(32), blk, 0, stream>>>(qkv, y);

  dim3 g2(N2 / 128, M / 128);
  gemm_relu_f32<<<g2, blk, 0, stream>>>(y, wo, out, M, N2, K, 0);
}

// Round 2
// 555.507 us; speedup vs baseline: 3.3662x; 3.3662x over previous
//
#include <hip/hip_runtime.h>
#include <hip/hip_bf16.h>

#define SEQ    2048
#define DMODEL 1024
#define NHEADS 16
#define HD     64
#define CS     64            // chunk size (timesteps)
#define NC     (SEQ / CS)    // 32 chunks per (b,h)
#define STSZ   (HD * HD + HD)  // 4160 floats per (b,h,chunk): KV[64][64] + ksum[64]
#define EPS_LA 1e-5f

// ---------------------------------------------------------------------------
// Tiled fp32 GEMM: C = A(MxK) * B(KxN), row-major, relu on cols < relu_limit.
// BM=BN=128, BK=8, 256 threads, 8x8 per thread.
// ---------------------------------------------------------------------------
__global__ __launch_bounds__(256) void gemm_relu_f32(
    const float* __restrict__ A, const float* __restrict__ B,
    float* __restrict__ C, int M, int N, int K, int relu_limit) {
  __shared__ float As[8][128];
  __shared__ float Bs[8][128];
  const int tid  = threadIdx.x;
  const int brow = blockIdx.y * 128;
  const int bcol = blockIdx.x * 128;
  const int tr = (tid >> 4) << 3;
  const int tc = (tid & 15) << 3;

  float acc[8][8];
  #pragma unroll
  for (int i = 0; i < 8; ++i)
    #pragma unroll
    for (int j = 0; j < 8; ++j) acc[i][j] = 0.f;

  const int ar  = tid >> 1;
  const int ak4 = (tid & 1) * 4;
  const int bk  = tid >> 5;
  const int bc4 = (tid & 31) * 4;

  const float* Aptr = A + (size_t)(brow + ar) * K + ak4;
  const float* Bptr = B + (size_t)bk * N + bcol + bc4;

  for (int k0 = 0; k0 < K; k0 += 8) {
    float4 av = *(const float4*)(Aptr + k0);
    float4 bv = *(const float4*)(Bptr + (size_t)k0 * N);
    As[ak4 + 0][ar] = av.x;
    As[ak4 + 1][ar] = av.y;
    As[ak4 + 2][ar] = av.z;
    As[ak4 + 3][ar] = av.w;
    *(float4*)&Bs[bk][bc4] = bv;
    __syncthreads();
    #pragma unroll
    for (int kk = 0; kk < 8; ++kk) {
      float ra[8], rb[8];
      #pragma unroll
      for (int i = 0; i < 8; ++i) ra[i] = As[kk][tr + i];
      #pragma unroll
      for (int j = 0; j < 8; ++j) rb[j] = Bs[kk][tc + j];
      #pragma unroll
      for (int i = 0; i < 8; ++i)
        #pragma unroll
        for (int j = 0; j < 8; ++j)
          acc[i][j] = fmaf(ra[i], rb[j], acc[i][j]);
    }
    __syncthreads();
  }

  #pragma unroll
  for (int i = 0; i < 8; ++i) {
    const int row = brow + tr + i;
    float* crow = C + (size_t)row * N + bcol;
    #pragma unroll
    for (int j = 0; j < 8; ++j) {
      float val = acc[i][j];
      if (bcol + tc + j < relu_limit) val = fmaxf(val, 0.f);
      crow[tc + j] = val;
    }
  }
}

// ---------------------------------------------------------------------------
// Kernel A: per-(b,h,chunk) sums.  KV_c[d][e] = sum_t k[t][d]*v[t][e],
// ksum_c[d] = sum_t k[t][d].  blockIdx.x = bh*NC + c.  256 threads.
// state[(bh*NC+c)][0..4095] = KV (row-major d,e), [4096..4159] = ksum.
// ---------------------------------------------------------------------------
__global__ __launch_bounds__(256) void chunk_sums(
    const float* __restrict__ qkv, float* __restrict__ state) {
  __shared__ float k_sh[CS * HD];
  __shared__ float v_sh[CS * HD];

  const int bh = blockIdx.x >> 5;      // NC = 32
  const int c  = blockIdx.x & (NC - 1);
  const int b  = bh >> 4;
  const int h  = bh & (NHEADS - 1);
  const int tid = threadIdx.x;

  const size_t rs   = 3 * DMODEL;
  const size_t base = ((size_t)(b * SEQ + c * CS)) * rs + (size_t)h * HD;

  // coalesced load: 1024 float4 per matrix, 4 per thread
  #pragma unroll
  for (int u = 0; u < 4; ++u) {
    const int f  = tid + 256 * u;       // float4 index
    const int t  = f >> 4;
    const int c4 = (f & 15) << 2;
    const float* src = qkv + base + (size_t)t * rs + c4;
    float4 kv = *(const float4*)(src + DMODEL);       // k (relu'd)
    float4 vv = *(const float4*)(src + 2 * DMODEL);   // v
    *(float4*)&k_sh[t * HD + c4] = kv;
    *(float4*)&v_sh[t * HD + c4] = vv;
  }
  __syncthreads();

  const int eo = tid & 63;
  const int dg = tid >> 6;             // wave id 0..3

  float kv[16];
  #pragma unroll
  for (int i = 0; i < 16; ++i) kv[i] = 0.f;

  #pragma unroll 2
  for (int t = 0; t < CS; ++t) {
    const float vv = v_sh[t * HD + eo];
    const float* kp = &k_sh[t * HD + dg * 16];
    #pragma unroll
    for (int i = 0; i < 16; ++i) kv[i] = fmaf(kp[i], vv, kv[i]);
  }

  float* st = state + (size_t)blockIdx.x * STSZ;
  #pragma unroll
  for (int i = 0; i < 16; ++i) st[(dg * 16 + i) * HD + eo] = kv[i];

  if (tid < HD) {
    float s = 0.f;
    #pragma unroll 4
    for (int t = 0; t < CS; ++t) s += k_sh[t * HD + tid];
    st[HD * HD + tid] = s;
  }
}

// ---------------------------------------------------------------------------
// Kernel B: in-place exclusive prefix over chunks, element-parallel.
// total elements = 32 bh * STSZ. Thread owns one element across all chunks.
// ---------------------------------------------------------------------------
__global__ __launch_bounds__(256) void chunk_prefix(float* __restrict__ state) {
  const int g = blockIdx.x * 256 + threadIdx.x;
  const int total = 2 * NHEADS * STSZ;
  if (g >= total) return;
  const int bh   = g / STSZ;
  const int elem = g - bh * STSZ;
  float* p = state + (size_t)bh * NC * STSZ + elem;

  float vals[NC];
  #pragma unroll
  for (int c = 0; c < NC; ++c) vals[c] = p[(size_t)c * STSZ];
  float run = 0.f;
  #pragma unroll
  for (int c = 0; c < NC; ++c) {
    const float t = vals[c];
    p[(size_t)c * STSZ] = run;
    run += t;
  }
}

// ---------------------------------------------------------------------------
// Kernel C: per-(b,h,chunk) output.
//   S[t][s] = q_t . k_s  (s<=t, else 0), stored transposed st_sh[s][t]
//   num[t][e] = sum_s S[t][s] v[s][e] + sum_d q[t][d] KVp[d][e]
//   den[t]    = sum_s S[t][s] + sum_d q[t][d] ksump[d] + eps
//   y[t][e]   = num/den
// ---------------------------------------------------------------------------
__global__ __launch_bounds__(256) void chunk_out(
    const float* __restrict__ qkv, const float* __restrict__ state,
    float* __restrict__ y) {
  __shared__ float q_sh[CS * 65];
  __shared__ float k_sh[CS * 65];
  __shared__ float st_sh[CS * 65];   // S transposed: st_sh[s*65 + t]
  __shared__ float v_sh[CS * HD];
  __shared__ float den_sh[CS];

  const int bh = blockIdx.x >> 5;
  const int c  = blockIdx.x & (NC - 1);
  const int b  = bh >> 4;
  const int h  = bh & (NHEADS - 1);
  const int tid = threadIdx.x;

  const size_t rs   = 3 * DMODEL;
  const size_t base = ((size_t)(b * SEQ + c * CS)) * rs + (size_t)h * HD;

  #pragma unroll
  for (int u = 0; u < 4; ++u) {
    const int f  = tid + 256 * u;
    const int t  = f >> 4;
    const int c4 = (f & 15) << 2;
    const float* src = qkv + base + (size_t)t * rs + c4;
    float4 qv = *(const float4*)(src);
    float4 kv = *(const float4*)(src + DMODEL);
    float4 vv = *(const float4*)(src + 2 * DMODEL);
    q_sh[t * 65 + c4 + 0] = qv.x;
    q_sh[t * 65 + c4 + 1] = qv.y;
    q_sh[t * 65 + c4 + 2] = qv.z;
    q_sh[t * 65 + c4 + 3] = qv.w;
    k_sh[t * 65 + c4 + 0] = kv.x;
    k_sh[t * 65 + c4 + 1] = kv.y;
    k_sh[t * 65 + c4 + 2] = kv.z;
    k_sh[t * 65 + c4 + 3] = kv.w;
    *(float4*)&v_sh[t * HD + c4] = vv;
  }
  __syncthreads();

  // ---- S = Q K^T (causal-masked), stored transposed ----
  {
    const int trow = tid >> 2;
    const int scb  = (tid & 3) << 4;
    float sacc[16];
    #pragma unroll
    for (int j = 0; j < 16; ++j) sacc[j] = 0.f;
    #pragma unroll
    for (int d0 = 0; d0 < HD; d0 += 16) {
      float qr[16];
      #pragma unroll
      for (int dd = 0; dd < 16; ++dd) qr[dd] = q_sh[trow * 65 + d0 + dd];
      #pragma unroll
      for (int j = 0; j < 16; ++j) {
        const float* kp = &k_sh[(scb + j) * 65 + d0];
        #pragma unroll
        for (int dd = 0; dd < 16; ++dd)
          sacc[j] = fmaf(qr[dd], kp[dd], sacc[j]);
      }
    }
    #pragma unroll
    for (int j = 0; j < 16; ++j)
      st_sh[(scb + j) * 65 + trow] = (scb + j <= trow) ? sacc[j] : 0.f;
  }
  __syncthreads();

  const float* kvp = state + ((size_t)bh * NC + c) * STSZ;

  // ---- den (wave 0) ----
  if (tid < CS) {
    float dsum = 0.f;
    #pragma unroll 4
    for (int s = 0; s < CS; ++s) dsum += st_sh[s * 65 + tid];
    const float* ksp = kvp + HD * HD;
    float dint = 0.f;
    #pragma unroll 4
    for (int d = 0; d < HD; ++d)
      dint = fmaf(q_sh[tid * 65 + d], ksp[d], dint);
    den_sh[tid] = dsum + dint + EPS_LA;
  }

  // ---- num: inter (q . KVp) + intra (S^T-weighted V) ----
  const int e  = tid & 63;
  const int tg = tid >> 6;
  float num[16];
  #pragma unroll
  for (int tt = 0; tt < 16; ++tt) num[tt] = 0.f;

  #pragma unroll 2
  for (int d = 0; d < HD; ++d) {
    const float kw = kvp[d * HD + e];
    const float* qp = &q_sh[(tg * 16) * 65 + d];
    #pragma unroll
    for (int tt = 0; tt < 16; ++tt)
      num[tt] = fmaf(qp[tt * 65], kw, num[tt]);
  }

  #pragma unroll 2
  for (int s = 0; s < CS; ++s) {
    const float vv = v_sh[s * HD + e];
    const float* sp = &st_sh[s * 65 + tg * 16];
    #pragma unroll
    for (int tt = 0; tt < 16; ++tt)
      num[tt] = fmaf(sp[tt], vv, num[tt]);
  }
  __syncthreads();   // den_sh ready for all

  #pragma unroll
  for (int tt = 0; tt < 16; ++tt) {
    const int t = tg * 16 + tt;
    y[((size_t)(b * SEQ + c * CS + t)) * DMODEL + (size_t)h * HD + e] =
        num[tt] / den_sh[t];
  }
}

// ---------------------------------------------------------------------------
extern "C" void kernel_launch(void* const* d_in, const int* in_sizes, int n_in,
                              void* d_out, int out_size, void* d_ws,
                              size_t ws_size, hipStream_t stream) {
  (void)in_sizes; (void)n_in; (void)out_size; (void)ws_size;
  const float* x    = (const float*)d_in[0];
  const float* wqkv = (const float*)d_in[1];
  const float* wo   = (const float*)d_in[2];
  float* out = (float*)d_out;

  const int M  = 2 * SEQ;     // 4096
  const int K  = DMODEL;      // 1024
  const int N1 = 3 * DMODEL;  // 3072
  const int N2 = DMODEL;      // 1024

  float* qkv   = (float*)d_ws;                       // 48 MB
  float* y     = qkv + (size_t)M * N1;               // 16 MB
  float* state = y + (size_t)M * N2;                 // 16.25 MB

  dim3 blk(256);
  gemm_relu_f32<<<dim3(N1 / 128, M / 128), blk, 0, stream>>>(
      x, wqkv, qkv, M, N1, K, 2 * DMODEL);

  chunk_sums<<<dim3(2 * NHEADS * NC), blk, 0, stream>>>(qkv, state);

  const int total = 2 * NHEADS * STSZ;
  chunk_prefix<<<dim3((total + 255) / 256), blk, 0, stream>>>(state);

  chunk_out<<<dim3(2 * NHEADS * NC), blk, 0, stream>>>(qkv, state, y);

  gemm_relu_f32<<<dim3(N2 / 128, M / 128), blk, 0, stream>>>(
      y, wo, out, M, N2, K, 0);
}

// Round 3
// 186.292 us; speedup vs baseline: 10.0376x; 2.9819x over previous
//
#include <hip/hip_runtime.h>
#include <hip/hip_bf16.h>

#define SEQ    2048
#define DMODEL 1024
#define NHEADS 16
#define HD     64
#define CS     64
#define NC     (SEQ / CS)
#define STSZ   (HD * HD + HD)
#define EPS_LA 1e-5f

typedef __attribute__((ext_vector_type(8))) short bf16x8;
typedef __attribute__((ext_vector_type(4))) float f32x4;

__device__ __forceinline__ void gload_lds16(const void* g, void* l) {
  __builtin_amdgcn_global_load_lds(
      (const __attribute__((address_space(1))) void*)g,
      (__attribute__((address_space(3))) void*)l, 16, 0, 0);
}

__device__ __forceinline__ ushort f2bf(float x) {
  __hip_bfloat16 h = __float2bfloat16(x);
  return __builtin_bit_cast(ushort, h);
}

// ---------------------------------------------------------------------------
// x (f32) -> bf16, elementwise. n4 = n/4 float4s, grid*256 == n4 exactly.
// ---------------------------------------------------------------------------
__global__ __launch_bounds__(256) void conv_bf16(
    const float* __restrict__ src, ushort* __restrict__ dst) {
  const int i = blockIdx.x * 256 + threadIdx.x;
  float4 v = *(const float4*)(src + (size_t)i * 4);
  ushort4 o;
  o.x = f2bf(v.x); o.y = f2bf(v.y); o.z = f2bf(v.z); o.w = f2bf(v.w);
  *(ushort4*)(dst + (size_t)i * 4) = o;
}

// ---------------------------------------------------------------------------
// src [R][Ncols] f32  ->  dst [Ncols][R] bf16   (64x64 LDS tiles)
// grid = (Ncols/64, R/64), 256 threads.
// ---------------------------------------------------------------------------
__global__ __launch_bounds__(256) void transpose_to_bf16(
    const float* __restrict__ src, ushort* __restrict__ dst, int R, int Ncols) {
  __shared__ float t[64][65];
  const int r0 = blockIdx.y * 64, c0 = blockIdx.x * 64;
  const int tid = threadIdx.x;
  const int lr = tid >> 2;
  const int lc = (tid & 3) * 16;
  const float* sp = src + (size_t)(r0 + lr) * Ncols + c0 + lc;
  #pragma unroll
  for (int j = 0; j < 4; ++j) {
    float4 v = *(const float4*)(sp + j * 4);
    t[lr][lc + j * 4 + 0] = v.x;
    t[lr][lc + j * 4 + 1] = v.y;
    t[lr][lc + j * 4 + 2] = v.z;
    t[lr][lc + j * 4 + 3] = v.w;
  }
  __syncthreads();
  ushort out[16];
  #pragma unroll
  for (int j = 0; j < 16; ++j)
    out[j] = f2bf(t[lc + j][lr]);
  ushort* dp = dst + (size_t)(c0 + lr) * R + r0 + lc;
  *(uint4*)dp = *(const uint4*)&out[0];
  *(uint4*)(dp + 8) = *(const uint4*)&out[8];
}

// ---------------------------------------------------------------------------
// bf16 MFMA GEMM: C(f32) = A(MxK bf16, row-major) * Bt(NxK bf16)^T
// relu on cols < relu_limit. 128x128 tile, BK=64, 4 waves (2x2), m97 structure.
// ---------------------------------------------------------------------------
__global__ __launch_bounds__(256) void gemm_bf16_mfma(
    const ushort* __restrict__ A, const ushort* __restrict__ Bt,
    float* __restrict__ C, int M, int N, int K, int relu_limit) {
  __shared__ ushort Asm[128 * 64];
  __shared__ ushort Bsm[128 * 64];

  const int tid  = threadIdx.x;
  const int lane = tid & 63;
  const int w    = tid >> 6;
  const int wr   = w >> 1, wc = w & 1;
  const int brow = blockIdx.y * 128;
  const int bcol = blockIdx.x * 128;

  f32x4 acc[4][4];
  #pragma unroll
  for (int i = 0; i < 4; ++i)
    #pragma unroll
    for (int j = 0; j < 4; ++j) acc[i][j] = (f32x4)0.f;

  // staging: chunk i = w*4+u covers LDS rows i*8..i*8+7 (1 KB each)
  const int arow = w * 32 + (lane >> 3);      // + u*8
  const int acol = (lane & 7) * 8;
  const ushort* Ag = A  + (size_t)(brow + arow) * K + acol;
  const ushort* Bg = Bt + (size_t)(bcol + arow) * K + acol;

  const int l15 = lane & 15;
  const int khi = (lane >> 4) * 8;

  for (int k0 = 0; k0 < K; k0 += 64) {
    #pragma unroll
    for (int u = 0; u < 4; ++u) {
      gload_lds16(Ag + k0 + (size_t)u * 8 * K, &Asm[(w * 4 + u) * 512]);
      gload_lds16(Bg + k0 + (size_t)u * 8 * K, &Bsm[(w * 4 + u) * 512]);
    }
    __syncthreads();
    #pragma unroll
    for (int kk = 0; kk < 2; ++kk) {
      const int ko = kk * 32 + khi;
      bf16x8 af[4], bfr[4];
      #pragma unroll
      for (int mi = 0; mi < 4; ++mi)
        af[mi] = *(const bf16x8*)&Asm[(wr * 64 + mi * 16 + l15) * 64 + ko];
      #pragma unroll
      for (int ni = 0; ni < 4; ++ni)
        bfr[ni] = *(const bf16x8*)&Bsm[(wc * 64 + ni * 16 + l15) * 64 + ko];
      #pragma unroll
      for (int mi = 0; mi < 4; ++mi)
        #pragma unroll
        for (int ni = 0; ni < 4; ++ni)
          acc[mi][ni] = __builtin_amdgcn_mfma_f32_16x16x32_bf16(
              af[mi], bfr[ni], acc[mi][ni], 0, 0, 0);
    }
    __syncthreads();
  }

  #pragma unroll
  for (int mi = 0; mi < 4; ++mi) {
    #pragma unroll
    for (int ni = 0; ni < 4; ++ni) {
      const int r0  = brow + wr * 64 + mi * 16 + (lane >> 4) * 4;
      const int col = bcol + wc * 64 + ni * 16 + l15;
      const bool rl = col < relu_limit;
      #pragma unroll
      for (int i = 0; i < 4; ++i) {
        float v = acc[mi][ni][i];
        if (rl) v = fmaxf(v, 0.f);
        C[(size_t)(r0 + i) * N + col] = v;
      }
    }
  }
}

// ---------------------------------------------------------------------------
// Kernel A: per-(b,h,chunk) sums. (unchanged from round 2)
// ---------------------------------------------------------------------------
__global__ __launch_bounds__(256) void chunk_sums(
    const float* __restrict__ qkv, float* __restrict__ state) {
  __shared__ float k_sh[CS * HD];
  __shared__ float v_sh[CS * HD];

  const int bh = blockIdx.x >> 5;
  const int c  = blockIdx.x & (NC - 1);
  const int b  = bh >> 4;
  const int h  = bh & (NHEADS - 1);
  const int tid = threadIdx.x;

  const size_t rs   = 3 * DMODEL;
  const size_t base = ((size_t)(b * SEQ + c * CS)) * rs + (size_t)h * HD;

  #pragma unroll
  for (int u = 0; u < 4; ++u) {
    const int f  = tid + 256 * u;
    const int t  = f >> 4;
    const int c4 = (f & 15) << 2;
    const float* src = qkv + base + (size_t)t * rs + c4;
    float4 kv = *(const float4*)(src + DMODEL);
    float4 vv = *(const float4*)(src + 2 * DMODEL);
    *(float4*)&k_sh[t * HD + c4] = kv;
    *(float4*)&v_sh[t * HD + c4] = vv;
  }
  __syncthreads();

  const int eo = tid & 63;
  const int dg = tid >> 6;

  float kv[16];
  #pragma unroll
  for (int i = 0; i < 16; ++i) kv[i] = 0.f;

  #pragma unroll 2
  for (int t = 0; t < CS; ++t) {
    const float vv = v_sh[t * HD + eo];
    const float* kp = &k_sh[t * HD + dg * 16];
    #pragma unroll
    for (int i = 0; i < 16; ++i) kv[i] = fmaf(kp[i], vv, kv[i]);
  }

  float* st = state + (size_t)blockIdx.x * STSZ;
  #pragma unroll
  for (int i = 0; i < 16; ++i) st[(dg * 16 + i) * HD + eo] = kv[i];

  if (tid < HD) {
    float s = 0.f;
    #pragma unroll 4
    for (int t = 0; t < CS; ++t) s += k_sh[t * HD + tid];
    st[HD * HD + tid] = s;
  }
}

// ---------------------------------------------------------------------------
// Kernel B: exclusive prefix over chunks, element-parallel. (unchanged)
// ---------------------------------------------------------------------------
__global__ __launch_bounds__(256) void chunk_prefix(float* __restrict__ state) {
  const int g = blockIdx.x * 256 + threadIdx.x;
  const int total = 2 * NHEADS * STSZ;
  if (g >= total) return;
  const int bh   = g / STSZ;
  const int elem = g - bh * STSZ;
  float* p = state + (size_t)bh * NC * STSZ + elem;

  float vals[NC];
  #pragma unroll
  for (int c = 0; c < NC; ++c) vals[c] = p[(size_t)c * STSZ];
  float run = 0.f;
  #pragma unroll
  for (int c = 0; c < NC; ++c) {
    const float t = vals[c];
    p[(size_t)c * STSZ] = run;
    run += t;
  }
}

// ---------------------------------------------------------------------------
// Kernel C: per-(b,h,chunk) output; now writes y as bf16.
// ---------------------------------------------------------------------------
__global__ __launch_bounds__(256) void chunk_out(
    const float* __restrict__ qkv, const float* __restrict__ state,
    ushort* __restrict__ y) {
  __shared__ float q_sh[CS * 65];
  __shared__ float k_sh[CS * 65];
  __shared__ float st_sh[CS * 65];
  __shared__ float v_sh[CS * HD];
  __shared__ float den_sh[CS];

  const int bh = blockIdx.x >> 5;
  const int c  = blockIdx.x & (NC - 1);
  const int b  = bh >> 4;
  const int h  = bh & (NHEADS - 1);
  const int tid = threadIdx.x;

  const size_t rs   = 3 * DMODEL;
  const size_t base = ((size_t)(b * SEQ + c * CS)) * rs + (size_t)h * HD;

  #pragma unroll
  for (int u = 0; u < 4; ++u) {
    const int f  = tid + 256 * u;
    const int t  = f >> 4;
    const int c4 = (f & 15) << 2;
    const float* src = qkv + base + (size_t)t * rs + c4;
    float4 qv = *(const float4*)(src);
    float4 kv = *(const float4*)(src + DMODEL);
    float4 vv = *(const float4*)(src + 2 * DMODEL);
    q_sh[t * 65 + c4 + 0] = qv.x;
    q_sh[t * 65 + c4 + 1] = qv.y;
    q_sh[t * 65 + c4 + 2] = qv.z;
    q_sh[t * 65 + c4 + 3] = qv.w;
    k_sh[t * 65 + c4 + 0] = kv.x;
    k_sh[t * 65 + c4 + 1] = kv.y;
    k_sh[t * 65 + c4 + 2] = kv.z;
    k_sh[t * 65 + c4 + 3] = kv.w;
    *(float4*)&v_sh[t * HD + c4] = vv;
  }
  __syncthreads();

  {
    const int trow = tid >> 2;
    const int scb  = (tid & 3) << 4;
    float sacc[16];
    #pragma unroll
    for (int j = 0; j < 16; ++j) sacc[j] = 0.f;
    #pragma unroll
    for (int d0 = 0; d0 < HD; d0 += 16) {
      float qr[16];
      #pragma unroll
      for (int dd = 0; dd < 16; ++dd) qr[dd] = q_sh[trow * 65 + d0 + dd];
      #pragma unroll
      for (int j = 0; j < 16; ++j) {
        const float* kp = &k_sh[(scb + j) * 65 + d0];
        #pragma unroll
        for (int dd = 0; dd < 16; ++dd)
          sacc[j] = fmaf(qr[dd], kp[dd], sacc[j]);
      }
    }
    #pragma unroll
    for (int j = 0; j < 16; ++j)
      st_sh[(scb + j) * 65 + trow] = (scb + j <= trow) ? sacc[j] : 0.f;
  }
  __syncthreads();

  const float* kvp = state + ((size_t)bh * NC + c) * STSZ;

  if (tid < CS) {
    float dsum = 0.f;
    #pragma unroll 4
    for (int s = 0; s < CS; ++s) dsum += st_sh[s * 65 + tid];
    const float* ksp = kvp + HD * HD;
    float dint = 0.f;
    #pragma unroll 4
    for (int d = 0; d < HD; ++d)
      dint = fmaf(q_sh[tid * 65 + d], ksp[d], dint);
    den_sh[tid] = dsum + dint + EPS_LA;
  }

  const int e  = tid & 63;
  const int tg = tid >> 6;
  float num[16];
  #pragma unroll
  for (int tt = 0; tt < 16; ++tt) num[tt] = 0.f;

  #pragma unroll 2
  for (int d = 0; d < HD; ++d) {
    const float kw = kvp[d * HD + e];
    const float* qp = &q_sh[(tg * 16) * 65 + d];
    #pragma unroll
    for (int tt = 0; tt < 16; ++tt)
      num[tt] = fmaf(qp[tt * 65], kw, num[tt]);
  }

  #pragma unroll 2
  for (int s = 0; s < CS; ++s) {
    const float vv = v_sh[s * HD + e];
    const float* sp = &st_sh[s * 65 + tg * 16];
    #pragma unroll
    for (int tt = 0; tt < 16; ++tt)
      num[tt] = fmaf(sp[tt], vv, num[tt]);
  }
  __syncthreads();

  #pragma unroll
  for (int tt = 0; tt < 16; ++tt) {
    const int t = tg * 16 + tt;
    y[((size_t)(b * SEQ + c * CS + t)) * DMODEL + (size_t)h * HD + e] =
        f2bf(num[tt] / den_sh[t]);
  }
}

// ---------------------------------------------------------------------------
extern "C" void kernel_launch(void* const* d_in, const int* in_sizes, int n_in,
                              void* d_out, int out_size, void* d_ws,
                              size_t ws_size, hipStream_t stream) {
  (void)in_sizes; (void)n_in; (void)out_size; (void)ws_size;
  const float* x    = (const float*)d_in[0];
  const float* wqkv = (const float*)d_in[1];
  const float* wo   = (const float*)d_in[2];
  float* out = (float*)d_out;

  const int M  = 2 * SEQ;     // 4096
  const int K  = DMODEL;      // 1024
  const int N1 = 3 * DMODEL;  // 3072
  const int N2 = DMODEL;      // 1024

  // workspace layout (80.25 MiB total, same footprint as round 2):
  float*  qkv   = (float*)d_ws;                        // 48 MiB
  float*  state = qkv + (size_t)M * N1;                // 16.25+ MiB
  ushort* xb    = (ushort*)(state + (size_t)2 * NHEADS * NC * STSZ); // 8 MiB
  ushort* yb    = xb;                                  // alias (disjoint in time)
  ushort* wqkvT = xb + (size_t)M * K;                  // 6 MiB
  ushort* woT   = wqkvT + (size_t)K * N1;              // 2 MiB

  dim3 blk(256);

  conv_bf16<<<dim3((M * K) / 1024), blk, 0, stream>>>(x, xb);
  transpose_to_bf16<<<dim3(N1 / 64, K / 64), blk, 0, stream>>>(wqkv, wqkvT, K, N1);
  transpose_to_bf16<<<dim3(N2 / 64, K / 64), blk, 0, stream>>>(wo, woT, K, N2);

  gemm_bf16_mfma<<<dim3(N1 / 128, M / 128), blk, 0, stream>>>(
      xb, wqkvT, qkv, M, N1, K, 2 * DMODEL);

  chunk_sums<<<dim3(2 * NHEADS * NC), blk, 0, stream>>>(qkv, state);

  const int total = 2 * NHEADS * STSZ;
  chunk_prefix<<<dim3((total + 255) / 256), blk, 0, stream>>>(state);

  chunk_out<<<dim3(2 * NHEADS * NC), blk, 0, stream>>>(qkv, state, yb);

  gemm_bf16_mfma<<<dim3(N2 / 128, M / 128), blk, 0, stream>>>(
      yb, woT, out, M, N2, K, 0);
}

// Round 5
// 116.608 us; speedup vs baseline: 16.0361x; 1.5976x over previous
//
#include <hip/hip_runtime.h>
#include <hip/hip_bf16.h>

#define SEQ    2048
#define DMODEL 1024
#define NHEADS 16
#define HD     64
#define CS     64
#define NC     (SEQ / CS)
#define STSZ   (HD * HD + HD)   // 4160 f32: KVT[64][64] + ksum[64]
#define EPS_LA 1e-5f
#define LP     72               // padded LDS row stride (bf16 elems)

typedef __attribute__((ext_vector_type(8))) short  bf16x8;
typedef __attribute__((ext_vector_type(8))) unsigned short ushort8;
typedef __attribute__((ext_vector_type(4))) float  f32x4;

__device__ __forceinline__ void gload_lds16(const void* g, void* l) {
  __builtin_amdgcn_global_load_lds(
      (const __attribute__((address_space(1))) void*)g,
      (__attribute__((address_space(3))) void*)l, 16, 0, 0);
}

__device__ __forceinline__ ushort f2bf(float x) {
  __hip_bfloat16 h = __float2bfloat16(x);
  return __builtin_bit_cast(ushort, h);
}
__device__ __forceinline__ float bf2f(ushort u) {
  unsigned int v = ((unsigned int)u) << 16;
  return __builtin_bit_cast(float, v);
}

// ---------------------------------------------------------------------------
// x (f32) -> bf16 elementwise
// ---------------------------------------------------------------------------
__global__ __launch_bounds__(256) void conv_bf16(
    const float* __restrict__ src, ushort* __restrict__ dst) {
  const int i = blockIdx.x * 256 + threadIdx.x;
  float4 v = *(const float4*)(src + (size_t)i * 4);
  ushort4 o;
  o.x = f2bf(v.x); o.y = f2bf(v.y); o.z = f2bf(v.z); o.w = f2bf(v.w);
  *(ushort4*)(dst + (size_t)i * 4) = o;
}

// ---------------------------------------------------------------------------
// src [R][Ncols] f32 -> dst [Ncols][R] bf16
// ---------------------------------------------------------------------------
__global__ __launch_bounds__(256) void transpose_to_bf16(
    const float* __restrict__ src, ushort* __restrict__ dst, int R, int Ncols) {
  __shared__ float t[64][65];
  const int r0 = blockIdx.y * 64, c0 = blockIdx.x * 64;
  const int tid = threadIdx.x;
  const int lr = tid >> 2;
  const int lc = (tid & 3) * 16;
  const float* sp = src + (size_t)(r0 + lr) * Ncols + c0 + lc;
  #pragma unroll
  for (int j = 0; j < 4; ++j) {
    float4 v = *(const float4*)(sp + j * 4);
    t[lr][lc + j * 4 + 0] = v.x;
    t[lr][lc + j * 4 + 1] = v.y;
    t[lr][lc + j * 4 + 2] = v.z;
    t[lr][lc + j * 4 + 3] = v.w;
  }
  __syncthreads();
  ushort out[16];
  #pragma unroll
  for (int j = 0; j < 16; ++j)
    out[j] = f2bf(t[lc + j][lr]);
  ushort* dp = dst + (size_t)(c0 + lr) * R + r0 + lc;
  *(uint4*)dp = *(const uint4*)&out[0];
  *(uint4*)(dp + 8) = *(const uint4*)&out[8];
}

// ---------------------------------------------------------------------------
// bf16 MFMA GEMM, f32 output: C = A(MxK) * Bt(NxK)^T, relu cols<relu_limit
// ---------------------------------------------------------------------------
__global__ __launch_bounds__(256) void gemm_bf16_f32out(
    const ushort* __restrict__ A, const ushort* __restrict__ Bt,
    float* __restrict__ C, int M, int N, int K, int relu_limit) {
  __shared__ ushort Asm[128 * 64];
  __shared__ ushort Bsm[128 * 64];

  const int tid  = threadIdx.x;
  const int lane = tid & 63;
  const int w    = tid >> 6;
  const int wr   = w >> 1, wc = w & 1;
  const int brow = blockIdx.y * 128;
  const int bcol = blockIdx.x * 128;

  f32x4 acc[4][4];
  #pragma unroll
  for (int i = 0; i < 4; ++i)
    #pragma unroll
    for (int j = 0; j < 4; ++j) acc[i][j] = (f32x4)0.f;

  const int arow = w * 32 + (lane >> 3);
  const int acol = (lane & 7) * 8;
  const ushort* Ag = A  + (size_t)(brow + arow) * K + acol;
  const ushort* Bg = Bt + (size_t)(bcol + arow) * K + acol;

  const int l15 = lane & 15;
  const int khi = (lane >> 4) * 8;

  for (int k0 = 0; k0 < K; k0 += 64) {
    #pragma unroll
    for (int u = 0; u < 4; ++u) {
      gload_lds16(Ag + k0 + (size_t)u * 8 * K, &Asm[(w * 4 + u) * 512]);
      gload_lds16(Bg + k0 + (size_t)u * 8 * K, &Bsm[(w * 4 + u) * 512]);
    }
    __syncthreads();
    #pragma unroll
    for (int kk = 0; kk < 2; ++kk) {
      const int ko = kk * 32 + khi;
      bf16x8 af[4], bfr[4];
      #pragma unroll
      for (int mi = 0; mi < 4; ++mi)
        af[mi] = *(const bf16x8*)&Asm[(wr * 64 + mi * 16 + l15) * 64 + ko];
      #pragma unroll
      for (int ni = 0; ni < 4; ++ni)
        bfr[ni] = *(const bf16x8*)&Bsm[(wc * 64 + ni * 16 + l15) * 64 + ko];
      #pragma unroll
      for (int mi = 0; mi < 4; ++mi)
        #pragma unroll
        for (int ni = 0; ni < 4; ++ni)
          acc[mi][ni] = __builtin_amdgcn_mfma_f32_16x16x32_bf16(
              af[mi], bfr[ni], acc[mi][ni], 0, 0, 0);
    }
    __syncthreads();
  }

  #pragma unroll
  for (int mi = 0; mi < 4; ++mi) {
    #pragma unroll
    for (int ni = 0; ni < 4; ++ni) {
      const int r0  = brow + wr * 64 + mi * 16 + (lane >> 4) * 4;
      const int col = bcol + wc * 64 + ni * 16 + l15;
      const bool rl = col < relu_limit;
      #pragma unroll
      for (int i = 0; i < 4; ++i) {
        float v = acc[mi][ni][i];
        if (rl) v = fmaxf(v, 0.f);
        C[(size_t)(r0 + i) * N + col] = v;
      }
    }
  }
}

// ---------------------------------------------------------------------------
// Same GEMM, bf16 output.
// ---------------------------------------------------------------------------
__global__ __launch_bounds__(256) void gemm_bf16_b16out(
    const ushort* __restrict__ A, const ushort* __restrict__ Bt,
    ushort* __restrict__ C, int M, int N, int K, int relu_limit) {
  __shared__ ushort Asm[128 * 64];
  __shared__ ushort Bsm[128 * 64];

  const int tid  = threadIdx.x;
  const int lane = tid & 63;
  const int w    = tid >> 6;
  const int wr   = w >> 1, wc = w & 1;
  const int brow = blockIdx.y * 128;
  const int bcol = blockIdx.x * 128;

  f32x4 acc[4][4];
  #pragma unroll
  for (int i = 0; i < 4; ++i)
    #pragma unroll
    for (int j = 0; j < 4; ++j) acc[i][j] = (f32x4)0.f;

  const int arow = w * 32 + (lane >> 3);
  const int acol = (lane & 7) * 8;
  const ushort* Ag = A  + (size_t)(brow + arow) * K + acol;
  const ushort* Bg = Bt + (size_t)(bcol + arow) * K + acol;

  const int l15 = lane & 15;
  const int khi = (lane >> 4) * 8;

  for (int k0 = 0; k0 < K; k0 += 64) {
    #pragma unroll
    for (int u = 0; u < 4; ++u) {
      gload_lds16(Ag + k0 + (size_t)u * 8 * K, &Asm[(w * 4 + u) * 512]);
      gload_lds16(Bg + k0 + (size_t)u * 8 * K, &Bsm[(w * 4 + u) * 512]);
    }
    __syncthreads();
    #pragma unroll
    for (int kk = 0; kk < 2; ++kk) {
      const int ko = kk * 32 + khi;
      bf16x8 af[4], bfr[4];
      #pragma unroll
      for (int mi = 0; mi < 4; ++mi)
        af[mi] = *(const bf16x8*)&Asm[(wr * 64 + mi * 16 + l15) * 64 + ko];
      #pragma unroll
      for (int ni = 0; ni < 4; ++ni)
        bfr[ni] = *(const bf16x8*)&Bsm[(wc * 64 + ni * 16 + l15) * 64 + ko];
      #pragma unroll
      for (int mi = 0; mi < 4; ++mi)
        #pragma unroll
        for (int ni = 0; ni < 4; ++ni)
          acc[mi][ni] = __builtin_amdgcn_mfma_f32_16x16x32_bf16(
              af[mi], bfr[ni], acc[mi][ni], 0, 0, 0);
    }
    __syncthreads();
  }

  #pragma unroll
  for (int mi = 0; mi < 4; ++mi) {
    #pragma unroll
    for (int ni = 0; ni < 4; ++ni) {
      const int r0  = brow + wr * 64 + mi * 16 + (lane >> 4) * 4;
      const int col = bcol + wc * 64 + ni * 16 + l15;
      const bool rl = col < relu_limit;
      #pragma unroll
      for (int i = 0; i < 4; ++i) {
        float v = acc[mi][ni][i];
        if (rl) v = fmaxf(v, 0.f);
        C[(size_t)(r0 + i) * N + col] = f2bf(v);
      }
    }
  }
}

// ---------------------------------------------------------------------------
// Kernel A (MFMA): state[bh,c] = { KVT[e][d] = sum_t V[t][e] K[t][d], ksum[d] }
// qkvb: (b, n, 3*DMODEL) bf16. blockIdx.x = bh*NC + c.
// ---------------------------------------------------------------------------
__global__ __launch_bounds__(256) void chunk_sums_mfma(
    const ushort* __restrict__ qkvb, float* __restrict__ state) {
  __shared__ ushort Kt[64 * LP];   // Kt[d][t]
  __shared__ ushort Vt[64 * LP];   // Vt[e][t]

  const int bh = blockIdx.x >> 5;
  const int c  = blockIdx.x & (NC - 1);
  const int b  = bh >> 4;
  const int h  = bh & (NHEADS - 1);
  const int tid = threadIdx.x;

  const size_t rs   = 3 * DMODEL;
  const size_t base = ((size_t)(b * SEQ + c * CS)) * rs + (size_t)h * HD;

  const int r  = tid >> 2;          // timestep row 0..63
  const int sg = (tid & 3) * 16;    // col segment
  {
    const ushort* src = qkvb + base + (size_t)r * rs + sg;
    ushort8 k0 = *(const ushort8*)(src + DMODEL);
    ushort8 k1 = *(const ushort8*)(src + DMODEL + 8);
    ushort8 v0 = *(const ushort8*)(src + 2 * DMODEL);
    ushort8 v1 = *(const ushort8*)(src + 2 * DMODEL + 8);
    #pragma unroll
    for (int j = 0; j < 8; ++j) {
      Kt[(sg + j) * LP + r]     = k0[j];
      Kt[(sg + 8 + j) * LP + r] = k1[j];
      Vt[(sg + j) * LP + r]     = v0[j];
      Vt[(sg + 8 + j) * LP + r] = v1[j];
    }
  }
  __syncthreads();

  const int lane = tid & 63;
  const int w    = tid >> 6;
  const int l15  = lane & 15;
  const int khi  = (lane >> 4) * 8;

  bf16x8 va[2];
  #pragma unroll
  for (int kk = 0; kk < 2; ++kk)
    va[kk] = *(const bf16x8*)&Vt[(w * 16 + l15) * LP + kk * 32 + khi];

  f32x4 a[4];
  #pragma unroll
  for (int ct = 0; ct < 4; ++ct) {
    a[ct] = (f32x4)0.f;
    #pragma unroll
    for (int kk = 0; kk < 2; ++kk)
      a[ct] = __builtin_amdgcn_mfma_f32_16x16x32_bf16(
          va[kk], *(const bf16x8*)&Kt[(ct * 16 + l15) * LP + kk * 32 + khi],
          a[ct], 0, 0, 0);
  }

  float* st = state + (size_t)blockIdx.x * STSZ;
  #pragma unroll
  for (int ct = 0; ct < 4; ++ct) {
    #pragma unroll
    for (int i = 0; i < 4; ++i) {
      const int e = w * 16 + (lane >> 4) * 4 + i;
      const int d = ct * 16 + l15;
      st[e * HD + d] = a[ct][i];
    }
  }

  if (tid < HD) {
    float s = 0.f;
    #pragma unroll 8
    for (int t = 0; t < CS; ++t) s += bf2f(Kt[tid * LP + t]);
    st[HD * HD + tid] = s;
  }
}

// ---------------------------------------------------------------------------
// Kernel B: exclusive prefix over chunks, element-parallel (fp32).
// ---------------------------------------------------------------------------
__global__ __launch_bounds__(256) void chunk_prefix(float* __restrict__ state) {
  const int g = blockIdx.x * 256 + threadIdx.x;
  const int total = 2 * NHEADS * STSZ;
  if (g >= total) return;
  const int bh   = g / STSZ;
  const int elem = g - bh * STSZ;
  float* p = state + (size_t)bh * NC * STSZ + elem;

  float vals[NC];
  #pragma unroll
  for (int c = 0; c < NC; ++c) vals[c] = p[(size_t)c * STSZ];
  float run = 0.f;
  #pragma unroll
  for (int c = 0; c < NC; ++c) {
    const float t = vals[c];
    p[(size_t)c * STSZ] = run;
    run += t;
  }
}

// ---------------------------------------------------------------------------
// Kernel C (MFMA): per-(b,h,chunk) output, writes y bf16.
//   S = Q K^T (causal mask in-register) -> Sm (bf16 LDS)
//   O[t][n] = Q @ KvAug + Sm @ VtAug, n=0..79:  cols 0..63 = num, col 64 = den
//   y = num / (den + eps)
// ---------------------------------------------------------------------------
__global__ __launch_bounds__(256) void chunk_out_mfma(
    const ushort* __restrict__ qkvb, const float* __restrict__ state,
    ushort* __restrict__ y) {
  __shared__ ushort Qs[64 * LP];   // Q[t][d]
  __shared__ ushort Ks[64 * LP];   // K[s][d]
  __shared__ ushort Vt[80 * LP];   // Vaug^T[n][s]: n<64 = V[s][n], n=64: ones
  __shared__ ushort Kv[80 * LP];   // KvAug^T[n][d]: n<64 = KVp[d][n], n=64: ksum
  __shared__ ushort Sm[64 * LP];   // masked S[t][s] bf16

  const int bh = blockIdx.x >> 5;
  const int c  = blockIdx.x & (NC - 1);
  const int b  = bh >> 4;
  const int h  = bh & (NHEADS - 1);
  const int tid = threadIdx.x;

  const size_t rs   = 3 * DMODEL;
  const size_t base = ((size_t)(b * SEQ + c * CS)) * rs + (size_t)h * HD;

  // ---- stage Q, K row-major; V transposed ----
  {
    const int r  = tid >> 2;
    const int sg = (tid & 3) * 16;
    const ushort* src = qkvb + base + (size_t)r * rs + sg;
    ushort8 q0 = *(const ushort8*)(src);
    ushort8 q1 = *(const ushort8*)(src + 8);
    ushort8 k0 = *(const ushort8*)(src + DMODEL);
    ushort8 k1 = *(const ushort8*)(src + DMODEL + 8);
    ushort8 v0 = *(const ushort8*)(src + 2 * DMODEL);
    ushort8 v1 = *(const ushort8*)(src + 2 * DMODEL + 8);
    *(ushort8*)&Qs[r * LP + sg]     = q0;
    *(ushort8*)&Qs[r * LP + sg + 8] = q1;
    *(ushort8*)&Ks[r * LP + sg]     = k0;
    *(ushort8*)&Ks[r * LP + sg + 8] = k1;
    #pragma unroll
    for (int j = 0; j < 8; ++j) {
      Vt[(sg + j) * LP + r]     = v0[j];
      Vt[(sg + 8 + j) * LP + r] = v1[j];
    }
  }
  // Vt rows 64..79: row 64 = 1.0, rest 0
  {
    const int idx = tid * 4;                 // 0..1023
    const int row = 64 + (idx >> 6);
    const int col = idx & 63;
    const ushort val = (row == 64) ? (ushort)0x3F80 : (ushort)0;
    ushort4 v4 = {val, val, val, val};
    *(ushort4*)&Vt[row * LP + col] = v4;
  }
  // Kv rows 0..63 from prefixed state (KVT, e-major), row 64 = ksum, 65..79 = 0
  {
    const float* sp = state + ((size_t)bh * NC + c) * STSZ;
    const int off = tid * 16;                // 0..4095
    const int e   = off >> 6;
    const int col = off & 63;
    ushort tmp[16];
    #pragma unroll
    for (int j = 0; j < 4; ++j) {
      float4 f = *(const float4*)(sp + off + j * 4);
      tmp[j * 4 + 0] = f2bf(f.x);
      tmp[j * 4 + 1] = f2bf(f.y);
      tmp[j * 4 + 2] = f2bf(f.z);
      tmp[j * 4 + 3] = f2bf(f.w);
    }
    *(ushort8*)&Kv[e * LP + col]     = *(const ushort8*)&tmp[0];
    *(ushort8*)&Kv[e * LP + col + 8] = *(const ushort8*)&tmp[8];
    if (tid < 16) {
      const int c4 = tid * 4;
      ushort4 v4;
      v4.x = f2bf(sp[HD * HD + c4 + 0]);
      v4.y = f2bf(sp[HD * HD + c4 + 1]);
      v4.z = f2bf(sp[HD * HD + c4 + 2]);
      v4.w = f2bf(sp[HD * HD + c4 + 3]);
      *(ushort4*)&Kv[64 * LP + c4] = v4;
    }
    if (tid < 240) {
      const int idx = tid * 4;               // 0..959
      const int row = 65 + (idx >> 6);
      const int col2 = idx & 63;
      ushort4 z = {0, 0, 0, 0};
      *(ushort4*)&Kv[row * LP + col2] = z;
    }
  }
  __syncthreads();

  const int lane = tid & 63;
  const int w    = tid >> 6;
  const int l15  = lane & 15;
  const int khi  = (lane >> 4) * 8;

  // ---- S = Q K^T for row stripe w*16..w*16+15 ----
  bf16x8 qa[2];
  #pragma unroll
  for (int kk = 0; kk < 2; ++kk)
    qa[kk] = *(const bf16x8*)&Qs[(w * 16 + l15) * LP + kk * 32 + khi];

  {
    f32x4 sac[4];
    #pragma unroll
    for (int ct = 0; ct < 4; ++ct) {
      sac[ct] = (f32x4)0.f;
      #pragma unroll
      for (int kk = 0; kk < 2; ++kk)
        sac[ct] = __builtin_amdgcn_mfma_f32_16x16x32_bf16(
            qa[kk], *(const bf16x8*)&Ks[(ct * 16 + l15) * LP + kk * 32 + khi],
            sac[ct], 0, 0, 0);
    }
    const int t0 = w * 16 + (lane >> 4) * 4;
    #pragma unroll
    for (int ct = 0; ct < 4; ++ct) {
      const int s = ct * 16 + l15;
      #pragma unroll
      for (int i = 0; i < 4; ++i) {
        const int t = t0 + i;
        const float v = (s <= t) ? sac[ct][i] : 0.f;
        Sm[t * LP + s] = f2bf(v);
      }
    }
  }
  __syncthreads();

  // ---- O = Q @ KvAug + Sm @ VtAug  (N = 80) ----
  bf16x8 sa[2];
  #pragma unroll
  for (int kk = 0; kk < 2; ++kk)
    sa[kk] = *(const bf16x8*)&Sm[(w * 16 + l15) * LP + kk * 32 + khi];

  f32x4 o[5];
  #pragma unroll
  for (int ct = 0; ct < 5; ++ct) {
    o[ct] = (f32x4)0.f;
    #pragma unroll
    for (int kk = 0; kk < 2; ++kk)
      o[ct] = __builtin_amdgcn_mfma_f32_16x16x32_bf16(
          qa[kk], *(const bf16x8*)&Kv[(ct * 16 + l15) * LP + kk * 32 + khi],
          o[ct], 0, 0, 0);
    #pragma unroll
    for (int kk = 0; kk < 2; ++kk)
      o[ct] = __builtin_amdgcn_mfma_f32_16x16x32_bf16(
          sa[kk], *(const bf16x8*)&Vt[(ct * 16 + l15) * LP + kk * 32 + khi],
          o[ct], 0, 0, 0);
  }

  // ---- epilogue: den broadcast within 16-lane group, write y ----
  float den[4];
  #pragma unroll
  for (int i = 0; i < 4; ++i)
    den[i] = __shfl(o[4][i], lane & 48) + EPS_LA;

  const int t0 = w * 16 + (lane >> 4) * 4;
  #pragma unroll
  for (int ct = 0; ct < 4; ++ct) {
    const int e = ct * 16 + l15;
    #pragma unroll
    for (int i = 0; i < 4; ++i) {
      const int t = t0 + i;
      y[((size_t)(b * SEQ + c * CS + t)) * DMODEL + (size_t)h * HD + e] =
          f2bf(o[ct][i] / den[i]);
    }
  }
}

// ---------------------------------------------------------------------------
extern "C" void kernel_launch(void* const* d_in, const int* in_sizes, int n_in,
                              void* d_out, int out_size, void* d_ws,
                              size_t ws_size, hipStream_t stream) {
  (void)in_sizes; (void)n_in; (void)out_size; (void)ws_size;
  const float* x    = (const float*)d_in[0];
  const float* wqkv = (const float*)d_in[1];
  const float* wo   = (const float*)d_in[2];
  float* out = (float*)d_out;

  const int M  = 2 * SEQ;     // 4096
  const int K  = DMODEL;      // 1024
  const int N1 = 3 * DMODEL;  // 3072
  const int N2 = DMODEL;      // 1024

  // workspace layout (~67.6 MiB)
  float*  state = (float*)d_ws;                           // 16.25 MiB
  ushort* qkvb  = (ushort*)(state + (size_t)2 * NHEADS * NC * STSZ); // 24 MiB
  ushort* xb    = qkvb + (size_t)M * N1;                  // 8 MiB
  ushort* yb    = xb + (size_t)M * K;                     // 8 MiB
  ushort* wqkvT = yb + (size_t)M * K;                     // 6 MiB
  ushort* woT   = wqkvT + (size_t)K * N1;                 // 2 MiB

  dim3 blk(256);

  conv_bf16<<<dim3((M * K) / 1024), blk, 0, stream>>>(x, xb);
  transpose_to_bf16<<<dim3(N1 / 64, K / 64), blk, 0, stream>>>(wqkv, wqkvT, K, N1);
  transpose_to_bf16<<<dim3(N2 / 64, K / 64), blk, 0, stream>>>(wo, woT, K, N2);

  gemm_bf16_b16out<<<dim3(N1 / 128, M / 128), blk, 0, stream>>>(
      xb, wqkvT, qkvb, M, N1, K, 2 * DMODEL);

  chunk_sums_mfma<<<dim3(2 * NHEADS * NC), blk, 0, stream>>>(qkvb, state);

  const int total = 2 * NHEADS * STSZ;
  chunk_prefix<<<dim3((total + 255) / 256), blk, 0, stream>>>(state);

  chunk_out_mfma<<<dim3(2 * NHEADS * NC), blk, 0, stream>>>(qkvb, state, yb);

  gemm_bf16_f32out<<<dim3(N2 / 128, M / 128), blk, 0, stream>>>(
      yb, woT, out, M, N2, K, 0);
}